// Round 1
// baseline (94.610 us; speedup 1.0000x reference)
//
#include <hip/hip_runtime.h>
#include <hip/hip_bf16.h>

// Problem constants (B=8, S=512, D=256, M=64, DE=256, H=8, DH=32).
// Key insight: activity = attn.mean over (H,S) == 1/S = 1/512 < 0.1 always
// (softmax rows sum to 1), so entity_mask == 0 and the returned graph == 0
// exactly. Only `entities` requires compute; refinement/gate MLPs are dead.

#define NS 512
#define ND 256
#define NB 8
#define NM 64
#define NH 8

// ---------------- x = emb + pos ----------------
__global__ __launch_bounds__(256) void add_pos_kernel(const float* __restrict__ emb,
        const float* __restrict__ pos, float* __restrict__ x) {
    int i = blockIdx.x * 256 + threadIdx.x;      // float4 index, total B*S*D/4 = 262144
    int dq = i & 63;                              // D/4 = 64 float4 per row
    int s  = (i >> 6) & 511;
    float4 e = ((const float4*)emb)[i];
    float4 p = ((const float4*)pos)[(s << 6) + dq];
    float4 r; r.x = e.x + p.x; r.y = e.y + p.y; r.z = e.z + p.z; r.w = e.w + p.w;
    ((float4*)x)[i] = r;
}

// ---------------- q = (lib @ wq) * rsqrt(DH) ----------------
__global__ __launch_bounds__(256) void qproj_kernel(const float* __restrict__ lib,
        const float* __restrict__ wq, float* __restrict__ q) {
    int m = blockIdx.x;            // 64
    int t = threadIdx.x;           // 256 output cols (h*32+dh)
    __shared__ float row[256];
    row[t] = lib[m * 256 + t];
    __syncthreads();
    float acc = 0.f;
    #pragma unroll 8
    for (int d = 0; d < 256; ++d) acc = fmaf(row[d], wq[d * 256 + t], acc);
    q[m * 256 + t] = acc * 0.17677669529663687f;   // 1/sqrt(32)
}

// ---------------- generic fp32 tiled GEMM: C[M,N] = A[M,K] @ B[K,N] ----------------
// BM=BN=64, BK=16, 256 threads, 4x4 micro-tile. grid=(M/64, N/64)
__global__ __launch_bounds__(256) void gemm_f32_kernel(const float* __restrict__ A,
        const float* __restrict__ Bm, float* __restrict__ C, int N, int K) {
    __shared__ float As[16][64];     // [k][m] (transposed A tile)
    __shared__ float Bs[16][64];     // [k][n]
    const int tid  = threadIdx.x;
    const int tr   = tid >> 4, tc = tid & 15;
    const int arow = tid >> 2, akq = (tid & 3) << 2;
    const int brow = tid >> 4, bnq = (tid & 15) << 2;
    float c[4][4] = {};
    const float* Ap = A + (size_t)(blockIdx.x * 64 + arow) * K + akq;
    const float* Bp = Bm + (size_t)brow * N + blockIdx.y * 64 + bnq;
    for (int k0 = 0; k0 < K; k0 += 16) {
        float4 av = *(const float4*)(Ap + k0);
        float4 bv = *(const float4*)(Bp + (size_t)k0 * N);
        As[akq    ][arow] = av.x;
        As[akq + 1][arow] = av.y;
        As[akq + 2][arow] = av.z;
        As[akq + 3][arow] = av.w;
        *(float4*)&Bs[brow][bnq] = bv;
        __syncthreads();
        #pragma unroll
        for (int kk = 0; kk < 16; ++kk) {
            float4 a4 = *(const float4*)&As[kk][tr << 2];
            float4 b4 = *(const float4*)&Bs[kk][tc << 2];
            float aa[4] = {a4.x, a4.y, a4.z, a4.w};
            float bb[4] = {b4.x, b4.y, b4.z, b4.w};
            #pragma unroll
            for (int i = 0; i < 4; ++i)
                #pragma unroll
                for (int j = 0; j < 4; ++j)
                    c[i][j] = fmaf(aa[i], bb[j], c[i][j]);
        }
        __syncthreads();
    }
    float* Cp = C + (size_t)(blockIdx.x * 64 + (tr << 2)) * N + blockIdx.y * 64 + (tc << 2);
    #pragma unroll
    for (int i = 0; i < 4; ++i)
        *(float4*)(Cp + (size_t)i * N) = make_float4(c[i][0], c[i][1], c[i][2], c[i][3]);
}

// ---------------- attention partials ----------------
// grid (b*H+h, s-quarter), 256 threads = 4 waves. lane = m (64 queries),
// each wave covers 32 s-rows with online softmax; k/v rows are wave-uniform.
__global__ __launch_bounds__(256) void attn_partial_kernel(const float* __restrict__ q,
        const float* __restrict__ k, const float* __restrict__ v, float* __restrict__ part) {
    const int bh = blockIdx.x;            // 0..63
    const int sq = blockIdx.y;            // 0..3
    const int b = bh >> 3, h = bh & 7;
    const int w = threadIdx.x >> 6;       // wave 0..3
    const int m = threadIdx.x & 63;       // query index
    const int s0 = sq * 128 + w * 32;

    float qr[32];
    {
        const float4* qp = (const float4*)(q + m * 256 + h * 32);
        #pragma unroll
        for (int u = 0; u < 8; ++u) {
            float4 t = qp[u];
            qr[4*u] = t.x; qr[4*u+1] = t.y; qr[4*u+2] = t.z; qr[4*u+3] = t.w;
        }
    }
    const float* kbase = k + ((size_t)(b * 512 + s0)) * 256 + h * 32;
    const float* vbase = v + ((size_t)(b * 512 + s0)) * 256 + h * 32;

    float Mx = -1e30f, sum = 0.f, acc[32];
    #pragma unroll
    for (int dh = 0; dh < 32; ++dh) acc[dh] = 0.f;

    #pragma unroll
    for (int cc = 0; cc < 4; ++cc) {          // 4 chunks of 8 s-rows
        float sc[8];
        #pragma unroll
        for (int i = 0; i < 8; ++i) {
            const float4* kr = (const float4*)(kbase + (size_t)(cc * 8 + i) * 256);
            float dsum = 0.f;
            #pragma unroll
            for (int u = 0; u < 8; ++u) {
                float4 kv = kr[u];
                dsum = fmaf(qr[4*u],   kv.x, dsum);
                dsum = fmaf(qr[4*u+1], kv.y, dsum);
                dsum = fmaf(qr[4*u+2], kv.z, dsum);
                dsum = fmaf(qr[4*u+3], kv.w, dsum);
            }
            sc[i] = dsum;
        }
        float cm = sc[0];
        #pragma unroll
        for (int i = 1; i < 8; ++i) cm = fmaxf(cm, sc[i]);
        float nm = fmaxf(Mx, cm);
        float f = __expf(Mx - nm);            // first iter: exp(-1e30) -> 0
        sum *= f;
        #pragma unroll
        for (int dh = 0; dh < 32; ++dh) acc[dh] *= f;
        #pragma unroll
        for (int i = 0; i < 8; ++i) {
            float p = __expf(sc[i] - nm);
            sum += p;
            const float4* vr = (const float4*)(vbase + (size_t)(cc * 8 + i) * 256);
            #pragma unroll
            for (int u = 0; u < 8; ++u) {
                float4 vv = vr[u];
                acc[4*u]   = fmaf(p, vv.x, acc[4*u]);
                acc[4*u+1] = fmaf(p, vv.y, acc[4*u+1]);
                acc[4*u+2] = fmaf(p, vv.z, acc[4*u+2]);
                acc[4*u+3] = fmaf(p, vv.w, acc[4*u+3]);
            }
        }
        Mx = nm;
    }
    // partial record: 36 floats (32 acc, M, sum, 2 pad) per (bh, sq, w, m)
    float* pp = part + ((size_t)((bh * 4 + sq) * 4 + w) * 64 + m) * 36;
    #pragma unroll
    for (int u = 0; u < 8; ++u)
        *(float4*)(pp + 4 * u) = make_float4(acc[4*u], acc[4*u+1], acc[4*u+2], acc[4*u+3]);
    pp[32] = Mx; pp[33] = sum;
}

// ---------------- combine 16 partials -> ctx[b,m,h,dh] ----------------
__global__ __launch_bounds__(256) void attn_combine_kernel(const float* __restrict__ part,
        float* __restrict__ ctx) {
    const int bh = blockIdx.x;            // 0..63
    const int b = bh >> 3, h = bh & 7;
    const int t = threadIdx.x;
    const int m = t >> 2, g = t & 3;      // 4 threads per m, 8 dh each
    const float* pb = part + (size_t)bh * 16 * 64 * 36 + m * 36;
    float Mj[16], Sj[16];
    float Mx = -1e30f;
    #pragma unroll
    for (int j = 0; j < 16; ++j) {
        Mj[j] = pb[(size_t)j * 64 * 36 + 32];
        Sj[j] = pb[(size_t)j * 64 * 36 + 33];
        Mx = fmaxf(Mx, Mj[j]);
    }
    float wgt[16]; float Ssum = 0.f;
    #pragma unroll
    for (int j = 0; j < 16; ++j) { wgt[j] = __expf(Mj[j] - Mx); Ssum = fmaf(wgt[j], Sj[j], Ssum); }
    float inv = 1.f / Ssum;
    float* op = ctx + ((size_t)(b * 64 + m)) * 256 + h * 32 + g * 8;
    #pragma unroll
    for (int u = 0; u < 8; ++u) {
        float num = 0.f;
        #pragma unroll
        for (int j = 0; j < 16; ++j) num = fmaf(wgt[j], pb[(size_t)j * 64 * 36 + g * 8 + u], num);
        op[u] = num * inv;
    }
}

extern "C" void kernel_launch(void* const* d_in, const int* in_sizes, int n_in,
                              void* d_out, int out_size, void* d_ws, size_t ws_size,
                              hipStream_t stream) {
    const float* emb = (const float*)d_in[0];
    const float* lib = (const float*)d_in[2];
    const float* pos = (const float*)d_in[3];
    const float* wq  = (const float*)d_in[4];
    const float* wk  = (const float*)d_in[5];
    const float* wv  = (const float*)d_in[6];
    const float* wo  = (const float*)d_in[7];
    float* out = (float*)d_out;

    float* ws  = (float*)d_ws;
    float* kbuf = ws;                       // 4096*256 = 1,048,576
    float* vbuf = kbuf + 1048576;           // 1,048,576
    float* qbuf = vbuf + 1048576;           // 16,384
    float* ctx  = qbuf + 16384;             // 131,072
    float* xbuf = ctx + 131072;             // 1,048,576
    float* part = xbuf;                     // aliases x (dead after GEMMs); 2,359,296

    add_pos_kernel<<<1024, 256, 0, stream>>>(emb, pos, xbuf);
    qproj_kernel<<<64, 256, 0, stream>>>(lib, wq, qbuf);

    dim3 gkv(64, 4);   // M=4096/64, N=256/64
    gemm_f32_kernel<<<gkv, 256, 0, stream>>>(xbuf, wk, kbuf, 256, 256);
    gemm_f32_kernel<<<gkv, 256, 0, stream>>>(xbuf, wv, vbuf, 256, 256);

    attn_partial_kernel<<<dim3(64, 4), 256, 0, stream>>>(qbuf, kbuf, vbuf, part);
    attn_combine_kernel<<<64, 256, 0, stream>>>(part, ctx);

    // entities = ctx[512,256] @ wo[256,256] -> d_out[0:131072]
    gemm_f32_kernel<<<dim3(8, 4), 256, 0, stream>>>(ctx, wo, out, 256, 256);

    // graph (32768) + entity_mask (512) are exactly zero: memset tail
    hipMemsetAsync(out + 131072, 0, (size_t)33280 * 4, stream);
}